// Round 10
// baseline (223.289 us; speedup 1.0000x reference)
//
#include <hip/hip_runtime.h>

typedef unsigned short u16;
typedef unsigned int u32;
typedef __attribute__((ext_vector_type(8))) short bf16x8;  // 8 bf16 = 4 VGPRs
typedef __attribute__((ext_vector_type(4))) float f32x4;
typedef __attribute__((ext_vector_type(16))) float f32x16;

// Problem constants
#define BB 2
#define SS 2048
#define DD 1024
#define HH 16
#define HD 64
#define MM (BB * SS)  // 4096

__device__ inline float u2f(u32 u) { return __uint_as_float(u); }
__device__ inline u16 f2bf(float f) {
  u32 u = __float_as_uint(f);
  return (u16)((u + 0x7fffu + ((u >> 16) & 1u)) >> 16);  // RNE
}

// async global->LDS DMA, 16B per lane. LDS dest must be wave-uniform base;
// HW adds lane*16B. Source is per-lane.
typedef const __attribute__((address_space(1))) void* gas_ptr;
typedef __attribute__((address_space(3))) void* las_ptr;
__device__ __forceinline__ void gll16(const void* g, void* l) {
  __builtin_amdgcn_global_load_lds((gas_ptr)g, (las_ptr)l, 16, 0, 0);
}

// truncation-pack two f32 -> packed bf16x2 (P values are in [0, 2^s], tolerance OK)
__device__ __forceinline__ u32 pk2(float a, float b) {
  return (__float_as_uint(a) >> 16) | (__float_as_uint(b) & 0xffff0000u);
}

// ---------------- fused prep: x->bf16 (z>=4) + W transpose->bf16 (z<4) ----------------
__global__ __launch_bounds__(256) void prep(const float* __restrict__ x, u16* __restrict__ xb,
                                            const float* __restrict__ W0, const float* __restrict__ W1,
                                            const float* __restrict__ W2, const float* __restrict__ W3,
                                            u16* __restrict__ Wt) {
  int z = blockIdx.z;
  int t = threadIdx.x;
  if (z >= 4) {
    int gid = (z - 4) * 256 + blockIdx.y * 16 + blockIdx.x;
    int i = (gid * 256 + t) * 8;
    float4 a = *(const float4*)(x + i);
    float4 b = *(const float4*)(x + i + 4);
    uint4 o;
    o.x = (u32)f2bf(a.x) | ((u32)f2bf(a.y) << 16);
    o.y = (u32)f2bf(a.z) | ((u32)f2bf(a.w) << 16);
    o.z = (u32)f2bf(b.x) | ((u32)f2bf(b.y) << 16);
    o.w = (u32)f2bf(b.z) | ((u32)f2bf(b.w) << 16);
    *(uint4*)(xb + i) = o;
    return;
  }
  const float* W = (z == 0) ? W0 : (z == 1) ? W1 : (z == 2) ? W2 : W3;
  u16* out = Wt + (size_t)z * (DD * DD);
  __shared__ __align__(16) u16 T[64][72];
  int n0 = blockIdx.x * 64, k0 = blockIdx.y * 64;
#pragma unroll
  for (int p = 0; p < 4; ++p) {
    int kr = (t >> 4) + p * 16;
    int c4 = (t & 15) * 4;
    float4 v = *(const float4*)&W[(size_t)(k0 + kr) * DD + n0 + c4];
    T[c4 + 0][kr] = f2bf(v.x);
    T[c4 + 1][kr] = f2bf(v.y);
    T[c4 + 2][kr] = f2bf(v.z);
    T[c4 + 3][kr] = f2bf(v.w);
  }
  __syncthreads();
#pragma unroll
  for (int p = 0; p < 2; ++p) {
    int n = (t >> 3) + p * 32;
    int c8 = (t & 7) * 8;
    uint4 v = *(const uint4*)&T[n][c8];
    *(uint4*)&out[(size_t)(n0 + n) * DD + k0 + c8] = v;
  }
}

// QKV projection: 128x128 tile, TRIPLE-buffered LDS via global_load_lds DMA with
// counted vmcnt (never drains to 0 in the main loop -- T3/T4). R6 version (best).
// 1D grid 768, XCD-swizzled. z=0: Q (pre-scaled). z=1: K. z=2: V transposed AND
// key-permuted (swap bits 2<->3 within each 64-key block -- matches attention's PV).
__global__ __launch_bounds__(256, 3) void gemm_qkv(const u16* __restrict__ xb, const u16* __restrict__ Wt,
                                                   const float* __restrict__ bq, const float* __restrict__ bk,
                                                   const float* __restrict__ bv,
                                                   u16* __restrict__ Qb, u16* __restrict__ Kb, u16* __restrict__ Vtb) {
  __shared__ __align__(16) u16 As[3 * 4096];  // 24 KB
  __shared__ __align__(16) u16 Bs[3 * 4096];  // 24 KB
  const int tid = threadIdx.x, lane = tid & 63, wv = tid >> 6;
  const int wm = (wv >> 1) * 64, wn = (wv & 1) * 64;
  const int l16 = lane & 15, quad = lane >> 4;

  // XCD-aware decode: same m-rows cluster on 2 XCDs, same n-cols on 4
  const int id = blockIdx.x;
  const int xcd = id & 7, inner = id >> 3;
  const int mg = xcd >> 1, ng = xcd & 1;
  const int im = inner & 7, rest = inner >> 3;
  const int in_ = rest & 3, z = rest >> 2;
  const int m0 = (mg * 8 + im) * 128, n0 = (ng * 4 + in_) * 128;

  const u16* Bt = Wt + (size_t)z * (DD * DD);
  const float* bias = (z == 0) ? bq : (z == 1) ? bk : bv;

  const int r0 = tid >> 2, k8 = (tid & 3) << 3;  // 64 rows x 4 chunks
  const u16* Ap0 = &xb[(size_t)(m0 + r0) * DD + k8];
  const u16* Ap1 = Ap0 + (size_t)64 * DD;
  const u16* Bp0 = &Bt[(size_t)(n0 + r0) * DD + k8];
  const u16* Bp1 = Bp0 + (size_t)64 * DD;

  const int ldst = wv * 512;  // wave-uniform LDS quarter base

  // prologue: tiles 0,1,2 -> bufs 0,1,2 (12 DMA ops)
#pragma unroll
  for (int p = 0; p < 3; ++p) {
    const int ko = p * 32, bo_ = p * 4096;
    gll16(Ap0 + ko, &As[bo_ + ldst]);
    gll16(Ap1 + ko, &As[bo_ + 2048 + ldst]);
    gll16(Bp0 + ko, &Bs[bo_ + ldst]);
    gll16(Bp1 + ko, &Bs[bo_ + 2048 + ldst]);
  }

  f32x4 acc[4][4];
  f32x4 zero = {0.f, 0.f, 0.f, 0.f};
#pragma unroll
  for (int i = 0; i < 4; ++i)
#pragma unroll
    for (int j = 0; j < 4; ++j) acc[i][j] = zero;

  asm volatile("s_waitcnt vmcnt(8)" ::: "memory");  // tile0 resident (own ops)
  __builtin_amdgcn_s_barrier();                     // -> everyone's tile0 resident

  int cur = 0;
  for (int t = 0; t < 32; ++t) {
    bf16x8 af[4], bg[4];
    const int cb = cur * 4096;
#pragma unroll
    for (int i = 0; i < 4; ++i) {
      af[i] = *(const bf16x8*)&As[cb + (wm + i * 16 + l16) * 32 + quad * 8];
      bg[i] = *(const bf16x8*)&Bs[cb + (wn + i * 16 + l16) * 32 + quad * 8];
    }
    asm volatile("s_waitcnt lgkmcnt(0)" ::: "memory");  // frags in regs
    __builtin_amdgcn_s_barrier();                       // all waves done reading buf cur
    if (t + 3 < 32) {                                   // reuse buf cur for tile t+3
      const int ko = (t + 3) * 32;
      gll16(Ap0 + ko, &As[cb + ldst]);
      gll16(Ap1 + ko, &As[cb + 2048 + ldst]);
      gll16(Bp0 + ko, &Bs[cb + ldst]);
      gll16(Bp1 + ko, &Bs[cb + 2048 + ldst]);
    }
    __builtin_amdgcn_sched_barrier(0);  // keep MFMAs below the DMA issue
#pragma unroll
    for (int i = 0; i < 4; ++i)
#pragma unroll
      for (int j = 0; j < 4; ++j)
        acc[i][j] = __builtin_amdgcn_mfma_f32_16x16x32_bf16(af[i], bg[j], acc[i][j], 0, 0, 0);
    // counted wait: tile t+1 complete, tiles t+2/t+3 stay in flight
    if (t <= 28)
      asm volatile("s_waitcnt vmcnt(8)" ::: "memory");
    else if (t == 29)
      asm volatile("s_waitcnt vmcnt(4)" ::: "memory");
    else if (t == 30)
      asm volatile("s_waitcnt vmcnt(0)" ::: "memory");
    if (t < 31) __builtin_amdgcn_s_barrier();
    cur = (cur == 2) ? 0 : cur + 1;
  }

  const float qsc = (z == 0) ? 0.180336880f : 1.0f;  // 1/sqrt(64) * log2(e)
  if (z == 2) {
    // V transposed + key-permuted (swap bits 2<->3 of s&63). s&63 bits: [5:4]=i,
    // [3:2]=quad, [1:0]=r -> key' = i*16 + (quad&1)*8 + (quad>>1)*4 + r.
#pragma unroll
    for (int i = 0; i < 4; ++i) {
#pragma unroll
      for (int j = 0; j < 4; ++j) {
        int col = n0 + wn + j * 16 + l16;
        float bcol = bias[col];
        int hh = col >> 6, dd = col & 63;
        int row0 = m0 + wm + i * 16;
        int bb = row0 >> 11, s0 = row0 & (SS - 1);
        int sbase = (s0 & ~63) + i * 16 + ((quad & 1) << 3) + ((quad >> 1) << 2);
        size_t base = (((size_t)((bb * HH + hh) * HD + dd)) << 11) + sbase;
        uint2 pv;
        pv.x = (u32)f2bf(acc[i][j][0] + bcol) | ((u32)f2bf(acc[i][j][1] + bcol) << 16);
        pv.y = (u32)f2bf(acc[i][j][2] + bcol) | ((u32)f2bf(acc[i][j][3] + bcol) << 16);
        *(uint2*)&Vtb[base] = pv;
      }
    }
  } else {
    u16* out = (z == 0) ? Qb : Kb;
#pragma unroll
    for (int i = 0; i < 4; ++i) {
#pragma unroll
      for (int j = 0; j < 4; ++j) {
        int col = n0 + wn + j * 16 + l16;
        float bcol = bias[col];
        int hh = col >> 6, dd = col & 63;
#pragma unroll
        for (int r = 0; r < 4; ++r) {
          int row = m0 + wm + i * 16 + quad * 4 + r;
          int bb = row >> 11, s = row & (SS - 1);
          out[((size_t)((bb * HH + hh) * SS + s) << 6) | dd] = f2bf((acc[i][j][r] + bcol) * qsc);
        }
      }
    }
  }
}

// Output projection, 128x64 tiles, TRIPLE-buffered + counted vmcnt, XCD-swizzled grid 512.
__global__ __launch_bounds__(256, 3) void gemm_out(const u16* __restrict__ Ub, const u16* __restrict__ Wot,
                                                   const float* __restrict__ bo, float* __restrict__ out) {
  __shared__ __align__(16) u16 As[3 * 4096];  // 24 KB
  __shared__ __align__(16) u16 Bs[3 * 2048];  // 12 KB
  const int tid = threadIdx.x, lane = tid & 63, wv = tid >> 6;
  const int wm = (wv >> 1) * 64, wn = (wv & 1) * 32;
  const int l16 = lane & 15, quad = lane >> 4;
  const int r0 = tid >> 2, k8 = (tid & 3) << 3;

  const int id = blockIdx.x;
  const int xcd = id & 7, inner = id >> 3;
  const int mg = xcd >> 1, ng = xcd & 1;
  const int im = inner & 7, in_ = inner >> 3;  // im 0..7, in_ 0..7
  const int m0 = (mg * 8 + im) * 128, n0 = (ng * 8 + in_) * 64;

  const u16* Ap0 = &Ub[(size_t)(m0 + r0) * DD + k8];
  const u16* Ap1 = Ap0 + (size_t)64 * DD;
  const u16* Bp0 = &Wot[(size_t)(n0 + r0) * DD + k8];

  const int ldst = wv * 512;

#pragma unroll
  for (int p = 0; p < 3; ++p) {
    const int ko = p * 32;
    gll16(Ap0 + ko, &As[p * 4096 + ldst]);
    gll16(Ap1 + ko, &As[p * 4096 + 2048 + ldst]);
    gll16(Bp0 + ko, &Bs[p * 2048 + ldst]);
  }

  f32x4 acc[4][2];
  f32x4 zero = {0.f, 0.f, 0.f, 0.f};
#pragma unroll
  for (int i = 0; i < 4; ++i) { acc[i][0] = zero; acc[i][1] = zero; }

  asm volatile("s_waitcnt vmcnt(6)" ::: "memory");
  __builtin_amdgcn_s_barrier();

  int cur = 0;
  for (int t = 0; t < 32; ++t) {
    bf16x8 af[4], bg[2];
#pragma unroll
    for (int i = 0; i < 4; ++i) af[i] = *(const bf16x8*)&As[cur * 4096 + (wm + i * 16 + l16) * 32 + quad * 8];
#pragma unroll
    for (int j = 0; j < 2; ++j) bg[j] = *(const bf16x8*)&Bs[cur * 2048 + (wn + j * 16 + l16) * 32 + quad * 8];
    asm volatile("s_waitcnt lgkmcnt(0)" ::: "memory");
    __builtin_amdgcn_s_barrier();
    if (t + 3 < 32) {
      const int ko = (t + 3) * 32;
      gll16(Ap0 + ko, &As[cur * 4096 + ldst]);
      gll16(Ap1 + ko, &As[cur * 4096 + 2048 + ldst]);
      gll16(Bp0 + ko, &Bs[cur * 2048 + ldst]);
    }
    __builtin_amdgcn_sched_barrier(0);
#pragma unroll
    for (int i = 0; i < 4; ++i)
#pragma unroll
      for (int j = 0; j < 2; ++j)
        acc[i][j] = __builtin_amdgcn_mfma_f32_16x16x32_bf16(af[i], bg[j], acc[i][j], 0, 0, 0);
    if (t <= 28)
      asm volatile("s_waitcnt vmcnt(6)" ::: "memory");
    else if (t == 29)
      asm volatile("s_waitcnt vmcnt(3)" ::: "memory");
    else if (t == 30)
      asm volatile("s_waitcnt vmcnt(0)" ::: "memory");
    if (t < 31) __builtin_amdgcn_s_barrier();
    cur = (cur == 2) ? 0 : cur + 1;
  }

#pragma unroll
  for (int i = 0; i < 4; ++i) {
#pragma unroll
    for (int j = 0; j < 2; ++j) {
      int col = n0 + wn + j * 16 + l16;
      float bcol = bo[col];
#pragma unroll
      for (int r = 0; r < 4; ++r) {
        int row = m0 + wm + i * 16 + quad * 4 + r;
        out[(size_t)row * DD + col] = acc[i][j][r] + bcol;
      }
    }
  }
}

// ---------------- MFMA flash attention: 64-q blocks x4/CU, 32x32 MFMAs, in-reg P ------
// R4/R6 math, halved block: 2 waves x 32 q = 64 q rows, 128 threads, grid 1024 -->
// 4 independent barrier domains per CU (R9 proved time ~ 1/blocks-per-CU; R7 proved
// more lockstep waves don't help). All 1024 blocks co-resident (33.4 KB LDS).
// Co-resident quads (same g, j=0..3) get qt in {g, 15-g, 16+g, 31-g}: per-CU tile-iter
// sum == 66 for every g -- exact balance, order-free.
// S^T = mfma_32x32x16(K, Q): lane (l31=q, hi) holds S[q][key = 32kt + 8p + 4hi + c].
// PV A-slot needs P[q][swap23(key)]; gemm_qkv stores V rows at key' = swap23(key) ->
// P stays entirely in registers.
__global__ __launch_bounds__(128, 2) void attention_mfma(const u16* __restrict__ Q, const u16* __restrict__ K,
                                                         const u16* __restrict__ Vt, u16* __restrict__ Uo) {
  const int tid = threadIdx.x, lane = tid & 63, wv = tid >> 6;  // 2 waves
  const int l31 = lane & 31, hi = lane >> 5;
  const int bh = blockIdx.x & 31;
  const int b = bh >> 4, h = bh & 15;
  const int j = blockIdx.x >> 8;         // 0..3 (dispatch quarter)
  const int g = (blockIdx.x >> 5) & 7;   // 0..7
  const int qt = (j == 0) ? g : (j == 1) ? (15 - g) : (j == 2) ? (16 + g) : (31 - g);
  const int qbase = qt * 64 + wv * 32;   // wave's 32 q rows
  const u16* Qh = Q + (size_t)(b * HH + h) * SS * HD;
  const u16* Kh = K + (size_t)(b * HH + h) * SS * HD;
  const u16* Vh = Vt + (size_t)(b * HH + h) * HD * SS;

  __shared__ __align__(16) u16 K_lds[2][4160];  // [buf][plane*520 + row*8 + e]
  __shared__ __align__(16) u16 V_lds[2][4160];
  __shared__ float lsc[64];

  // Q B-fragments: qf[m] holds Q[qbase+l31][d = 16m + 8hi .. +8]
  bf16x8 qf[4];
  {
    const u16* qp = &Qh[(size_t)(qbase + l31) * HD + 8 * hi];
#pragma unroll
    for (int m = 0; m < 4; ++m) qf[m] = *(const bf16x8*)(qp + 16 * m);
  }

  f32x16 o0, o1;
#pragma unroll
  for (int i = 0; i < 16; ++i) { o0[i] = 0.f; o1[i] = 0.f; }
  float lsum = 0.f;

  // staging: 128 threads, 64B contiguous per thread (4 x uint4), one tile = 8 KB K + 8 KB V
  const int sr = tid >> 1, c0 = (tid & 1) << 2;  // row, first of 4 planes
  const u16* Kg = &Kh[(size_t)sr * HD + c0 * 8];
  const u16* Vg = &Vh[(size_t)sr * SS + c0 * 8];
  const int ktiles = qt + 1;

  // prologue: tile0 -> LDS buf0; tile1 -> regs (addresses always valid, S=2048)
  uint4 kr[4], vr[4];
#pragma unroll
  for (int pp = 0; pp < 4; ++pp) {
    kr[pp] = *(const uint4*)(Kg + pp * 8);
    vr[pp] = *(const uint4*)(Vg + pp * 8);
    *(uint4*)&K_lds[0][(c0 + pp) * 520 + sr * 8] = kr[pp];
    *(uint4*)&V_lds[0][(c0 + pp) * 520 + sr * 8] = vr[pp];
  }
  {
    const u16* Kn = Kg + (size_t)64 * HD;
    const u16* Vn = Vg + 64;
#pragma unroll
    for (int pp = 0; pp < 4; ++pp) {
      kr[pp] = *(const uint4*)(Kn + pp * 8);
      vr[pp] = *(const uint4*)(Vn + pp * 8);
    }
  }
  __syncthreads();

  for (int t = 0; t < ktiles; ++t) {
    const int cur = t & 1;
    // S^T = K Q: two key-halves (rows l31 / 32+l31), d-chain of 4 (k=16 each)
    f32x16 s0, s1;
#pragma unroll
    for (int i = 0; i < 16; ++i) { s0[i] = 0.f; s1[i] = 0.f; }
#pragma unroll
    for (int m = 0; m < 4; ++m) {
      const u16* kp = &K_lds[cur][(2 * m + hi) * 520 + l31 * 8];
      bf16x8 kf0 = *(const bf16x8*)kp;
      bf16x8 kf1 = *(const bf16x8*)(kp + 256);
      s0 = __builtin_amdgcn_mfma_f32_32x32x16_bf16(kf0, qf[m], s0, 0, 0, 0);
      s1 = __builtin_amdgcn_mfma_f32_32x32x16_bf16(kf1, qf[m], s1, 0, 0, 0);
    }
    // p = exp2(s); mask only when tile touches the diagonal for this wave
#pragma unroll
    for (int i = 0; i < 16; ++i) {
      s0[i] = __builtin_amdgcn_exp2f(s0[i]);
      s1[i] = __builtin_amdgcn_exp2f(s1[i]);
    }
    if (64 * t + 63 > qbase) {
      const int qq = qbase + l31, kb0 = 64 * t + 4 * hi;
#pragma unroll
      for (int p = 0; p < 4; ++p)
#pragma unroll
        for (int c = 0; c < 4; ++c) {
          if (kb0 + 8 * p + c > qq) s0[4 * p + c] = 0.f;
          if (kb0 + 32 + 8 * p + c > qq) s1[4 * p + c] = 0.f;
        }
    }
#pragma unroll
    for (int i = 0; i < 16; ++i) lsum += s0[i] + s1[i];

    // PV: A packed from S-regs (kt = m>>1, regs 8(m&1)..+8), B = V planes
#pragma unroll
    for (int m = 0; m < 4; ++m) {
      const int p0 = 8 * (m & 1);
      union { uint4 u; bf16x8 v; } pa;
      if (m < 2) {
        pa.u.x = pk2(s0[p0 + 0], s0[p0 + 1]);
        pa.u.y = pk2(s0[p0 + 2], s0[p0 + 3]);
        pa.u.z = pk2(s0[p0 + 4], s0[p0 + 5]);
        pa.u.w = pk2(s0[p0 + 6], s0[p0 + 7]);
      } else {
        pa.u.x = pk2(s1[p0 + 0], s1[p0 + 1]);
        pa.u.y = pk2(s1[p0 + 2], s1[p0 + 3]);
        pa.u.z = pk2(s1[p0 + 4], s1[p0 + 5]);
        pa.u.w = pk2(s1[p0 + 6], s1[p0 + 7]);
      }
      const u16* vp = &V_lds[cur][(2 * m + hi) * 520 + l31 * 8];
      bf16x8 vf0 = *(const bf16x8*)vp;
      bf16x8 vf1 = *(const bf16x8*)(vp + 256);
      o0 = __builtin_amdgcn_mfma_f32_32x32x16_bf16(pa.v, vf0, o0, 0, 0, 0);
      o1 = __builtin_amdgcn_mfma_f32_32x32x16_bf16(pa.v, vf1, o1, 0, 0, 0);
    }

    // store prefetched tile t+1 into the other buffer; prefetch tile t+2
    if (t + 1 < ktiles) {
      const int nxt = cur ^ 1;
#pragma unroll
      for (int pp = 0; pp < 4; ++pp) {
        *(uint4*)&K_lds[nxt][(c0 + pp) * 520 + sr * 8] = kr[pp];
        *(uint4*)&V_lds[nxt][(c0 + pp) * 520 + sr * 8] = vr[pp];
      }
      if (t + 2 < ktiles) {
        const u16* Kn = Kg + (size_t)(t + 2) * 64 * HD;
        const u16* Vn = Vg + (t + 2) * 64;
#pragma unroll
        for (int pp = 0; pp < 4; ++pp) {
          kr[pp] = *(const uint4*)(Kn + pp * 8);
          vr[pp] = *(const uint4*)(Vn + pp * 8);
        }
      }
    }
    __syncthreads();
  }

  // l[q] lives at lanes q and q+32: fold halves, publish per-wave, read per O-row
  lsum += __shfl_xor(lsum, 32);
  if (hi == 0) lsc[wv * 32 + l31] = 1.0f / lsum;
  __syncthreads();
  f32x4 lv[4];
#pragma unroll
  for (int p = 0; p < 4; ++p) lv[p] = *(const f32x4*)&lsc[wv * 32 + 8 * p + 4 * hi];

  // epilogue: O C-layout row(q_local) = 8p + 4hi + c, col(d) = l31 (+32 for o1)
  u16* ub = Uo + (size_t)(b * SS) * DD + (h << 6);
#pragma unroll
  for (int p = 0; p < 4; ++p) {
#pragma unroll
    for (int c = 0; c < 4; ++c) {
      int row = qbase + 8 * p + 4 * hi + c;
      ub[(size_t)row * DD + l31] = f2bf(o0[4 * p + c] * lv[p][c]);
      ub[(size_t)row * DD + 32 + l31] = f2bf(o1[4 * p + c] * lv[p][c]);
    }
  }
}

extern "C" void kernel_launch(void* const* d_in, const int* in_sizes, int n_in,
                              void* d_out, int out_size, void* d_ws, size_t ws_size,
                              hipStream_t stream) {
  const float* x  = (const float*)d_in[0];
  const float* Wq = (const float*)d_in[1];
  const float* bq = (const float*)d_in[2];
  const float* Wk = (const float*)d_in[3];
  const float* bk = (const float*)d_in[4];
  const float* Wv = (const float*)d_in[5];
  const float* bv = (const float*)d_in[6];
  const float* Wo = (const float*)d_in[7];
  const float* bo = (const float*)d_in[8];
  float* out = (float*)d_out;

  // workspace layout (48 MB used)
  char* ws = (char*)d_ws;
  u16* xb  = (u16*)(ws);                       // 8 MB  x bf16 [4096][1024]
  u16* Wt  = (u16*)(ws + ((size_t)8 << 20));   // 8 MB  Wt[4][1024][1024] bf16 (q,k,v,o)
  u16* Qb  = (u16*)(ws + ((size_t)16 << 20));  // 8 MB  [B,H,S,HD] (pre-scaled)
  u16* Kb  = (u16*)(ws + ((size_t)24 << 20));  // 8 MB  [B,H,S,HD]
  u16* Vtb = (u16*)(ws + ((size_t)32 << 20));  // 8 MB  [B,H,HD,S] key'-permuted (swap23)
  u16* Ub  = (u16*)(ws + ((size_t)40 << 20));  // 8 MB  [4096][1024]

  prep<<<dim3(16, 16, 12), dim3(256), 0, stream>>>(x, xb, Wq, Wk, Wv, Wo, Wt);
  gemm_qkv<<<dim3(768), dim3(256), 0, stream>>>(xb, Wt, bq, bk, bv, Qb, Kb, Vtb);
  attention_mfma<<<dim3(1024), dim3(128), 0, stream>>>(Qb, Kb, Vtb, Ub);
  gemm_out<<<dim3(512), dim3(256), 0, stream>>>(Ub, Wt + (size_t)3 * DD * DD, bo, out);
}

// Round 11
// 167.370 us; speedup vs baseline: 1.3341x; 1.3341x over previous
//
#include <hip/hip_runtime.h>

typedef unsigned short u16;
typedef unsigned int u32;
typedef __attribute__((ext_vector_type(8))) short bf16x8;  // 8 bf16 = 4 VGPRs
typedef __attribute__((ext_vector_type(4))) float f32x4;
typedef __attribute__((ext_vector_type(16))) float f32x16;

// Problem constants
#define BB 2
#define SS 2048
#define DD 1024
#define HH 16
#define HD 64
#define MM (BB * SS)  // 4096

__device__ inline float u2f(u32 u) { return __uint_as_float(u); }
__device__ inline u16 f2bf(float f) {
  u32 u = __float_as_uint(f);
  return (u16)((u + 0x7fffu + ((u >> 16) & 1u)) >> 16);  // RNE
}

// async global->LDS DMA, 16B per lane. LDS dest must be wave-uniform base;
// HW adds lane*16B. Source is per-lane.
typedef const __attribute__((address_space(1))) void* gas_ptr;
typedef __attribute__((address_space(3))) void* las_ptr;
__device__ __forceinline__ void gll16(const void* g, void* l) {
  __builtin_amdgcn_global_load_lds((gas_ptr)g, (las_ptr)l, 16, 0, 0);
}

// truncation-pack two f32 -> packed bf16x2 (P values are in [0, 2^s], tolerance OK)
__device__ __forceinline__ u32 pk2(float a, float b) {
  return (__float_as_uint(a) >> 16) | (__float_as_uint(b) & 0xffff0000u);
}

// ---------------- fused prep: x->bf16 (z>=4) + W transpose->bf16 (z<4) ----------------
__global__ __launch_bounds__(256) void prep(const float* __restrict__ x, u16* __restrict__ xb,
                                            const float* __restrict__ W0, const float* __restrict__ W1,
                                            const float* __restrict__ W2, const float* __restrict__ W3,
                                            u16* __restrict__ Wt) {
  int z = blockIdx.z;
  int t = threadIdx.x;
  if (z >= 4) {
    int gid = (z - 4) * 256 + blockIdx.y * 16 + blockIdx.x;
    int i = (gid * 256 + t) * 8;
    float4 a = *(const float4*)(x + i);
    float4 b = *(const float4*)(x + i + 4);
    uint4 o;
    o.x = (u32)f2bf(a.x) | ((u32)f2bf(a.y) << 16);
    o.y = (u32)f2bf(a.z) | ((u32)f2bf(a.w) << 16);
    o.z = (u32)f2bf(b.x) | ((u32)f2bf(b.y) << 16);
    o.w = (u32)f2bf(b.z) | ((u32)f2bf(b.w) << 16);
    *(uint4*)(xb + i) = o;
    return;
  }
  const float* W = (z == 0) ? W0 : (z == 1) ? W1 : (z == 2) ? W2 : W3;
  u16* out = Wt + (size_t)z * (DD * DD);
  __shared__ __align__(16) u16 T[64][72];
  int n0 = blockIdx.x * 64, k0 = blockIdx.y * 64;
#pragma unroll
  for (int p = 0; p < 4; ++p) {
    int kr = (t >> 4) + p * 16;
    int c4 = (t & 15) * 4;
    float4 v = *(const float4*)&W[(size_t)(k0 + kr) * DD + n0 + c4];
    T[c4 + 0][kr] = f2bf(v.x);
    T[c4 + 1][kr] = f2bf(v.y);
    T[c4 + 2][kr] = f2bf(v.z);
    T[c4 + 3][kr] = f2bf(v.w);
  }
  __syncthreads();
#pragma unroll
  for (int p = 0; p < 2; ++p) {
    int n = (t >> 3) + p * 32;
    int c8 = (t & 7) * 8;
    uint4 v = *(const uint4*)&T[n][c8];
    *(uint4*)&out[(size_t)(n0 + n) * DD + k0 + c8] = v;
  }
}

// QKV projection: 128x128 tile, TRIPLE-buffered LDS via global_load_lds DMA with
// counted vmcnt (never drains to 0 in the main loop -- T3/T4).
// 1D grid 768, XCD-swizzled. z=0: Q (pre-scaled). z=1: K. z=2: V transposed AND
// key-permuted (swap bits 2<->3 within each 64-key block -- matches attention's PV).
__global__ __launch_bounds__(256, 3) void gemm_qkv(const u16* __restrict__ xb, const u16* __restrict__ Wt,
                                                   const float* __restrict__ bq, const float* __restrict__ bk,
                                                   const float* __restrict__ bv,
                                                   u16* __restrict__ Qb, u16* __restrict__ Kb, u16* __restrict__ Vtb) {
  __shared__ __align__(16) u16 As[3 * 4096];  // 24 KB
  __shared__ __align__(16) u16 Bs[3 * 4096];  // 24 KB
  const int tid = threadIdx.x, lane = tid & 63, wv = tid >> 6;
  const int wm = (wv >> 1) * 64, wn = (wv & 1) * 64;
  const int l16 = lane & 15, quad = lane >> 4;

  // XCD-aware decode: same m-rows cluster on 2 XCDs, same n-cols on 4
  const int id = blockIdx.x;
  const int xcd = id & 7, inner = id >> 3;
  const int mg = xcd >> 1, ng = xcd & 1;
  const int im = inner & 7, rest = inner >> 3;
  const int in_ = rest & 3, z = rest >> 2;
  const int m0 = (mg * 8 + im) * 128, n0 = (ng * 4 + in_) * 128;

  const u16* Bt = Wt + (size_t)z * (DD * DD);
  const float* bias = (z == 0) ? bq : (z == 1) ? bk : bv;

  const int r0 = tid >> 2, k8 = (tid & 3) << 3;  // 64 rows x 4 chunks
  const u16* Ap0 = &xb[(size_t)(m0 + r0) * DD + k8];
  const u16* Ap1 = Ap0 + (size_t)64 * DD;
  const u16* Bp0 = &Bt[(size_t)(n0 + r0) * DD + k8];
  const u16* Bp1 = Bp0 + (size_t)64 * DD;

  const int ldst = wv * 512;  // wave-uniform LDS quarter base

  // prologue: tiles 0,1,2 -> bufs 0,1,2 (12 DMA ops)
#pragma unroll
  for (int p = 0; p < 3; ++p) {
    const int ko = p * 32, bo_ = p * 4096;
    gll16(Ap0 + ko, &As[bo_ + ldst]);
    gll16(Ap1 + ko, &As[bo_ + 2048 + ldst]);
    gll16(Bp0 + ko, &Bs[bo_ + ldst]);
    gll16(Bp1 + ko, &Bs[bo_ + 2048 + ldst]);
  }

  f32x4 acc[4][4];
  f32x4 zero = {0.f, 0.f, 0.f, 0.f};
#pragma unroll
  for (int i = 0; i < 4; ++i)
#pragma unroll
    for (int j = 0; j < 4; ++j) acc[i][j] = zero;

  asm volatile("s_waitcnt vmcnt(8)" ::: "memory");  // tile0 resident (own ops)
  __builtin_amdgcn_s_barrier();                     // -> everyone's tile0 resident

  int cur = 0;
  for (int t = 0; t < 32; ++t) {
    bf16x8 af[4], bg[4];
    const int cb = cur * 4096;
#pragma unroll
    for (int i = 0; i < 4; ++i) {
      af[i] = *(const bf16x8*)&As[cb + (wm + i * 16 + l16) * 32 + quad * 8];
      bg[i] = *(const bf16x8*)&Bs[cb + (wn + i * 16 + l16) * 32 + quad * 8];
    }
    asm volatile("s_waitcnt lgkmcnt(0)" ::: "memory");  // frags in regs
    __builtin_amdgcn_s_barrier();                       // all waves done reading buf cur
    if (t + 3 < 32) {                                   // reuse buf cur for tile t+3
      const int ko = (t + 3) * 32;
      gll16(Ap0 + ko, &As[cb + ldst]);
      gll16(Ap1 + ko, &As[cb + 2048 + ldst]);
      gll16(Bp0 + ko, &Bs[cb + ldst]);
      gll16(Bp1 + ko, &Bs[cb + 2048 + ldst]);
    }
    __builtin_amdgcn_sched_barrier(0);  // keep MFMAs below the DMA issue
#pragma unroll
    for (int i = 0; i < 4; ++i)
#pragma unroll
      for (int j = 0; j < 4; ++j)
        acc[i][j] = __builtin_amdgcn_mfma_f32_16x16x32_bf16(af[i], bg[j], acc[i][j], 0, 0, 0);
    // counted wait: tile t+1 complete, tiles t+2/t+3 stay in flight
    if (t <= 28)
      asm volatile("s_waitcnt vmcnt(8)" ::: "memory");
    else if (t == 29)
      asm volatile("s_waitcnt vmcnt(4)" ::: "memory");
    else if (t == 30)
      asm volatile("s_waitcnt vmcnt(0)" ::: "memory");
    if (t < 31) __builtin_amdgcn_s_barrier();
    cur = (cur == 2) ? 0 : cur + 1;
  }

  const float qsc = (z == 0) ? 0.180336880f : 1.0f;  // 1/sqrt(64) * log2(e)
  if (z == 2) {
    // V transposed + key-permuted (swap bits 2<->3 of s&63). s&63 bits: [5:4]=i,
    // [3:2]=quad, [1:0]=r -> key' = i*16 + (quad&1)*8 + (quad>>1)*4 + r.
#pragma unroll
    for (int i = 0; i < 4; ++i) {
#pragma unroll
      for (int j = 0; j < 4; ++j) {
        int col = n0 + wn + j * 16 + l16;
        float bcol = bias[col];
        int hh = col >> 6, dd = col & 63;
        int row0 = m0 + wm + i * 16;
        int bb = row0 >> 11, s0 = row0 & (SS - 1);
        int sbase = (s0 & ~63) + i * 16 + ((quad & 1) << 3) + ((quad >> 1) << 2);
        size_t base = (((size_t)((bb * HH + hh) * HD + dd)) << 11) + sbase;
        uint2 pv;
        pv.x = (u32)f2bf(acc[i][j][0] + bcol) | ((u32)f2bf(acc[i][j][1] + bcol) << 16);
        pv.y = (u32)f2bf(acc[i][j][2] + bcol) | ((u32)f2bf(acc[i][j][3] + bcol) << 16);
        *(uint2*)&Vtb[base] = pv;
      }
    }
  } else {
    u16* out = (z == 0) ? Qb : Kb;
#pragma unroll
    for (int i = 0; i < 4; ++i) {
#pragma unroll
      for (int j = 0; j < 4; ++j) {
        int col = n0 + wn + j * 16 + l16;
        float bcol = bias[col];
        int hh = col >> 6, dd = col & 63;
#pragma unroll
        for (int r = 0; r < 4; ++r) {
          int row = m0 + wm + i * 16 + quad * 4 + r;
          int bb = row >> 11, s = row & (SS - 1);
          out[((size_t)((bb * HH + hh) * SS + s) << 6) | dd] = f2bf((acc[i][j][r] + bcol) * qsc);
        }
      }
    }
  }
}

// Output projection, 128x64 tiles, TRIPLE-buffered + counted vmcnt, XCD-swizzled grid 512.
__global__ __launch_bounds__(256, 3) void gemm_out(const u16* __restrict__ Ub, const u16* __restrict__ Wot,
                                                   const float* __restrict__ bo, float* __restrict__ out) {
  __shared__ __align__(16) u16 As[3 * 4096];  // 24 KB
  __shared__ __align__(16) u16 Bs[3 * 2048];  // 12 KB
  const int tid = threadIdx.x, lane = tid & 63, wv = tid >> 6;
  const int wm = (wv >> 1) * 64, wn = (wv & 1) * 32;
  const int l16 = lane & 15, quad = lane >> 4;
  const int r0 = tid >> 2, k8 = (tid & 3) << 3;

  const int id = blockIdx.x;
  const int xcd = id & 7, inner = id >> 3;
  const int mg = xcd >> 1, ng = xcd & 1;
  const int im = inner & 7, in_ = inner >> 3;  // im 0..7, in_ 0..7
  const int m0 = (mg * 8 + im) * 128, n0 = (ng * 8 + in_) * 64;

  const u16* Ap0 = &Ub[(size_t)(m0 + r0) * DD + k8];
  const u16* Ap1 = Ap0 + (size_t)64 * DD;
  const u16* Bp0 = &Wot[(size_t)(n0 + r0) * DD + k8];

  const int ldst = wv * 512;

#pragma unroll
  for (int p = 0; p < 3; ++p) {
    const int ko = p * 32;
    gll16(Ap0 + ko, &As[p * 4096 + ldst]);
    gll16(Ap1 + ko, &As[p * 4096 + 2048 + ldst]);
    gll16(Bp0 + ko, &Bs[p * 2048 + ldst]);
  }

  f32x4 acc[4][2];
  f32x4 zero = {0.f, 0.f, 0.f, 0.f};
#pragma unroll
  for (int i = 0; i < 4; ++i) { acc[i][0] = zero; acc[i][1] = zero; }

  asm volatile("s_waitcnt vmcnt(6)" ::: "memory");
  __builtin_amdgcn_s_barrier();

  int cur = 0;
  for (int t = 0; t < 32; ++t) {
    bf16x8 af[4], bg[2];
#pragma unroll
    for (int i = 0; i < 4; ++i) af[i] = *(const bf16x8*)&As[cur * 4096 + (wm + i * 16 + l16) * 32 + quad * 8];
#pragma unroll
    for (int j = 0; j < 2; ++j) bg[j] = *(const bf16x8*)&Bs[cur * 2048 + (wn + j * 16 + l16) * 32 + quad * 8];
    asm volatile("s_waitcnt lgkmcnt(0)" ::: "memory");
    __builtin_amdgcn_s_barrier();
    if (t + 3 < 32) {
      const int ko = (t + 3) * 32;
      gll16(Ap0 + ko, &As[cur * 4096 + ldst]);
      gll16(Ap1 + ko, &As[cur * 4096 + 2048 + ldst]);
      gll16(Bp0 + ko, &Bs[cur * 2048 + ldst]);
    }
    __builtin_amdgcn_sched_barrier(0);
#pragma unroll
    for (int i = 0; i < 4; ++i)
#pragma unroll
      for (int j = 0; j < 2; ++j)
        acc[i][j] = __builtin_amdgcn_mfma_f32_16x16x32_bf16(af[i], bg[j], acc[i][j], 0, 0, 0);
    if (t <= 28)
      asm volatile("s_waitcnt vmcnt(6)" ::: "memory");
    else if (t == 29)
      asm volatile("s_waitcnt vmcnt(3)" ::: "memory");
    else if (t == 30)
      asm volatile("s_waitcnt vmcnt(0)" ::: "memory");
    if (t < 31) __builtin_amdgcn_s_barrier();
    cur = (cur == 2) ? 0 : cur + 1;
  }

#pragma unroll
  for (int i = 0; i < 4; ++i) {
#pragma unroll
    for (int j = 0; j < 2; ++j) {
      int col = n0 + wn + j * 16 + l16;
      float bcol = bo[col];
#pragma unroll
      for (int r = 0; r < 4; ++r) {
        int row = m0 + wm + i * 16 + quad * 4 + r;
        out[(size_t)row * DD + col] = acc[i][j][r] + bcol;
      }
    }
  }
}

// ---------------- MFMA flash attention: 32x32 MFMAs, 32 q/wave, in-register P ----------
// (R4/R6 version -- best measured configuration.)
// Grid 512: bh = id&31 (same (b,h) -> same XCD), q-block pairing qb(i)+qb(i+256)=15 so
// co-resident pairs sum to 34 tile-iters. Block = 4 waves x 32 q = 128 q rows.
// S^T = mfma_32x32x16(K, Q): lane (l31=q, hi) holds S[q][key = 32kt + 8p + 4hi + c]
// (reg = 4p+c of tile kt). PV A-slot (m,hi,e) needs P[q][swap23(16m+8hi+e)] which is
// exactly S tile m>>1, reg 8(m&1)+4(e>>2)+(e&3) -- so P stays in registers, and
// gemm_qkv stores V rows at key' = swap23(key).
__global__ __launch_bounds__(256, 2) void attention_mfma(const u16* __restrict__ Q, const u16* __restrict__ K,
                                                         const u16* __restrict__ Vt, u16* __restrict__ Uo) {
  const int tid = threadIdx.x, lane = tid & 63, wv = tid >> 6;
  const int l31 = lane & 31, hi = lane >> 5;
  const int bh = blockIdx.x & 31;
  const int b = bh >> 4, h = bh & 15;
  const int g = blockIdx.x >> 5;                           // 0..15
  const int qb = (blockIdx.x < 256) ? (15 - g) : (g - 8);  // pairs (i,i+256) sum to 15
  const int q0 = qb * 128;
  const int qbase = q0 + wv * 32;  // wave's 32 q rows
  const u16* Qh = Q + (size_t)(b * HH + h) * SS * HD;
  const u16* Kh = K + (size_t)(b * HH + h) * SS * HD;
  const u16* Vh = Vt + (size_t)(b * HH + h) * HD * SS;

  __shared__ __align__(16) u16 K_lds[2][4160];  // [buf][plane*520 + row*8 + e]
  __shared__ __align__(16) u16 V_lds[2][4160];
  __shared__ float lsc[128];

  // Q B-fragments: qf[m] holds Q[qbase+l31][d = 16m + 8hi .. +8]
  bf16x8 qf[4];
  {
    const u16* qp = &Qh[(size_t)(qbase + l31) * HD + 8 * hi];
#pragma unroll
    for (int m = 0; m < 4; ++m) qf[m] = *(const bf16x8*)(qp + 16 * m);
  }

  f32x16 o0, o1;
#pragma unroll
  for (int i = 0; i < 16; ++i) { o0[i] = 0.f; o1[i] = 0.f; }
  float lsum = 0.f;

  const int sr = tid >> 2, ci = tid & 3;
  const u16* Kg = &Kh[(size_t)sr * HD + ci * 8];
  const u16* Vg = &Vh[(size_t)sr * SS + ci * 8];
  const int ktiles = 2 * qb + 2;
  const int w0 = ci * 520 + sr * 8, w1 = (ci + 4) * 520 + sr * 8;

  // prologue: tile0 -> LDS buf0; tile1 -> regs (ktiles >= 2 always)
  uint4 ka = *(const uint4*)Kg, kb = *(const uint4*)(Kg + 32);
  uint4 va = *(const uint4*)Vg, vb = *(const uint4*)(Vg + 32);
  *(uint4*)&K_lds[0][w0] = ka;
  *(uint4*)&K_lds[0][w1] = kb;
  *(uint4*)&V_lds[0][w0] = va;
  *(uint4*)&V_lds[0][w1] = vb;
  {
    const u16* Kn = Kg + (size_t)64 * HD;
    const u16* Vn = Vg + 64;
    ka = *(const uint4*)Kn; kb = *(const uint4*)(Kn + 32);
    va = *(const uint4*)Vn; vb = *(const uint4*)(Vn + 32);
  }
  __syncthreads();

  for (int t = 0; t < ktiles; ++t) {
    const int cur = t & 1;
    if (64 * t <= qbase + 31) {  // wave has unmasked keys in this tile
      // S^T = K Q: two key-halves (rows l31 / 32+l31), d-chain of 4 (k=16 each)
      f32x16 s0, s1;
#pragma unroll
      for (int i = 0; i < 16; ++i) { s0[i] = 0.f; s1[i] = 0.f; }
#pragma unroll
      for (int m = 0; m < 4; ++m) {
        const u16* kp = &K_lds[cur][(2 * m + hi) * 520 + l31 * 8];
        bf16x8 kf0 = *(const bf16x8*)kp;
        bf16x8 kf1 = *(const bf16x8*)(kp + 256);
        s0 = __builtin_amdgcn_mfma_f32_32x32x16_bf16(kf0, qf[m], s0, 0, 0, 0);
        s1 = __builtin_amdgcn_mfma_f32_32x32x16_bf16(kf1, qf[m], s1, 0, 0, 0);
      }
      // p = exp2(s); mask only when tile touches the diagonal for this wave
#pragma unroll
      for (int i = 0; i < 16; ++i) {
        s0[i] = __builtin_amdgcn_exp2f(s0[i]);
        s1[i] = __builtin_amdgcn_exp2f(s1[i]);
      }
      if (64 * t + 63 > qbase) {
        const int qq = qbase + l31, kb0 = 64 * t + 4 * hi;
#pragma unroll
        for (int p = 0; p < 4; ++p)
#pragma unroll
          for (int c = 0; c < 4; ++c) {
            if (kb0 + 8 * p + c > qq) s0[4 * p + c] = 0.f;
            if (kb0 + 32 + 8 * p + c > qq) s1[4 * p + c] = 0.f;
          }
      }
#pragma unroll
      for (int i = 0; i < 16; ++i) lsum += s0[i] + s1[i];

      // PV: A packed from S-regs (kt = m>>1, regs 8(m&1)..+8), B = V planes
#pragma unroll
      for (int m = 0; m < 4; ++m) {
        const int p0 = 8 * (m & 1);
        union { uint4 u; bf16x8 v; } pa;
        if (m < 2) {
          pa.u.x = pk2(s0[p0 + 0], s0[p0 + 1]);
          pa.u.y = pk2(s0[p0 + 2], s0[p0 + 3]);
          pa.u.z = pk2(s0[p0 + 4], s0[p0 + 5]);
          pa.u.w = pk2(s0[p0 + 6], s0[p0 + 7]);
        } else {
          pa.u.x = pk2(s1[p0 + 0], s1[p0 + 1]);
          pa.u.y = pk2(s1[p0 + 2], s1[p0 + 3]);
          pa.u.z = pk2(s1[p0 + 4], s1[p0 + 5]);
          pa.u.w = pk2(s1[p0 + 6], s1[p0 + 7]);
        }
        const u16* vp = &V_lds[cur][(2 * m + hi) * 520 + l31 * 8];
        bf16x8 vf0 = *(const bf16x8*)vp;
        bf16x8 vf1 = *(const bf16x8*)(vp + 256);
        o0 = __builtin_amdgcn_mfma_f32_32x32x16_bf16(pa.v, vf0, o0, 0, 0, 0);
        o1 = __builtin_amdgcn_mfma_f32_32x32x16_bf16(pa.v, vf1, o1, 0, 0, 0);
      }
    }

    // store prefetched tile t+1 into the other buffer; prefetch tile t+2
    if (t + 1 < ktiles) {
      const int nxt = cur ^ 1;
      *(uint4*)&K_lds[nxt][w0] = ka;
      *(uint4*)&K_lds[nxt][w1] = kb;
      *(uint4*)&V_lds[nxt][w0] = va;
      *(uint4*)&V_lds[nxt][w1] = vb;
      if (t + 2 < ktiles) {
        const u16* Kn = Kg + (size_t)(t + 2) * 64 * HD;
        const u16* Vn = Vg + (t + 2) * 64;
        ka = *(const uint4*)Kn; kb = *(const uint4*)(Kn + 32);
        va = *(const uint4*)Vn; vb = *(const uint4*)(Vn + 32);
      }
    }
    __syncthreads();
  }

  // l[q] lives at lanes q and q+32: fold halves, publish per-wave, read per O-row
  lsum += __shfl_xor(lsum, 32);
  if (hi == 0) lsc[wv * 32 + l31] = 1.0f / lsum;
  __syncthreads();
  f32x4 lv[4];
#pragma unroll
  for (int p = 0; p < 4; ++p) lv[p] = *(const f32x4*)&lsc[wv * 32 + 8 * p + 4 * hi];

  // epilogue: O C-layout row(q_local) = 8p + 4hi + c, col(d) = l31 (+32 for o1)
  u16* ub = Uo + (size_t)(b * SS) * DD + (h << 6);
#pragma unroll
  for (int p = 0; p < 4; ++p) {
#pragma unroll
    for (int c = 0; c < 4; ++c) {
      int row = qbase + 8 * p + 4 * hi + c;
      ub[(size_t)row * DD + l31] = f2bf(o0[4 * p + c] * lv[p][c]);
      ub[(size_t)row * DD + 32 + l31] = f2bf(o1[4 * p + c] * lv[p][c]);
    }
  }
}

extern "C" void kernel_launch(void* const* d_in, const int* in_sizes, int n_in,
                              void* d_out, int out_size, void* d_ws, size_t ws_size,
                              hipStream_t stream) {
  const float* x  = (const float*)d_in[0];
  const float* Wq = (const float*)d_in[1];
  const float* bq = (const float*)d_in[2];
  const float* Wk = (const float*)d_in[3];
  const float* bk = (const float*)d_in[4];
  const float* Wv = (const float*)d_in[5];
  const float* bv = (const float*)d_in[6];
  const float* Wo = (const float*)d_in[7];
  const float* bo = (const float*)d_in[8];
  float* out = (float*)d_out;

  // workspace layout (48 MB used)
  char* ws = (char*)d_ws;
  u16* xb  = (u16*)(ws);                       // 8 MB  x bf16 [4096][1024]
  u16* Wt  = (u16*)(ws + ((size_t)8 << 20));   // 8 MB  Wt[4][1024][1024] bf16 (q,k,v,o)
  u16* Qb  = (u16*)(ws + ((size_t)16 << 20));  // 8 MB  [B,H,S,HD] (pre-scaled)
  u16* Kb  = (u16*)(ws + ((size_t)24 << 20));  // 8 MB  [B,H,S,HD]
  u16* Vtb = (u16*)(ws + ((size_t)32 << 20));  // 8 MB  [B,H,HD,S] key'-permuted (swap23)
  u16* Ub  = (u16*)(ws + ((size_t)40 << 20));  // 8 MB  [4096][1024]

  prep<<<dim3(16, 16, 12), dim3(256), 0, stream>>>(x, xb, Wq, Wk, Wv, Wo, Wt);
  gemm_qkv<<<dim3(768), dim3(256), 0, stream>>>(xb, Wt, bq, bk, bv, Qb, Kb, Vtb);
  attention_mfma<<<dim3(512), dim3(256), 0, stream>>>(Qb, Kb, Vtb, Ub);
  gemm_out<<<dim3(512), dim3(256), 0, stream>>>(Ub, Wt + (size_t)3 * DD * DD, bo, out);
}